// Round 5
// baseline (242.604 us; speedup 1.0000x reference)
//
#include <hip/hip_runtime.h>
#include <math.h>

#define B 128
#define T 1024
#define H 256
#define L 16
#define INV_TEMP (1.0f/0.07f)
#define NEG_INF -1e30f

// ws layout (only seg<nseg regions are ever written/read -> no memset):
//   ws_pp   : float[B][4][L][H]   per-seg prototype partial sums   8 MB
//   ws_cntp : int[B][4][L]        per-seg label counts             32 KB
//   ws_dots : float[2][B][T][L]   partial dots per H-half          16 MB

// ---------------------------------------------------------------------------
// Kernel 1: prototype partial sums. grid = B * 4 segs = 512 blocks (2/CU).
// Lane covers the FULL 256-ch row as one float4 (16B/lane, 1KB/wave/token).
// Wave-private 16KB LDS slab: per token one ds_read_b32 (label) + b128 RMW.
// DS ops are in-order per wave -> RMW chains safe even with repeated labels.
__global__ __launch_bounds__(256) void proto_kernel(
    const float* __restrict__ feat, const int* __restrict__ dlen,
    const int* __restrict__ labels, float* __restrict__ ws_pp,
    int* __restrict__ ws_cntp) {
  __shared__ float acc[4][L * H];   // 64 KB, wave-private slabs
  __shared__ int labs[256];
  __shared__ int cnt[L];

  const int bx = blockIdx.x;
  const int b = bx >> 2;
  const int seg = bx & 3;
  const int tid = threadIdx.x;
  const int w = tid >> 6;
  const int lane = tid & 63;

  const int len = dlen[b];
  if (seg * 256 >= len) return;   // invalid segment: consumers skip seg>=nseg

  {
    float4* az = (float4*)acc;
    for (int i = tid; i < 4 * L * H / 4; i += 256)
      az[i] = make_float4(0.f, 0.f, 0.f, 0.f);
  }
  labs[tid] = labels[(size_t)b * T + seg * 256 + tid];
  if (tid < L) cnt[tid] = 0;
  __syncthreads();

  if ((seg * 256 + tid) < len) atomicAdd(&cnt[labs[tid]], 1);

  int nt = len - seg * 256 - w * 64;   // tokens this wave processes
  if (nt > 64) nt = 64;
  const float4* fbase = (const float4*)(feat +
      ((size_t)b * T + seg * 256 + w * 64) * H);
  float* a = acc[w];

  int j = 0;
  for (; j + 2 <= nt; j += 2) {
    float4 f0 = fbase[(size_t)(j + 0) * 64 + lane];
    float4 f1 = fbase[(size_t)(j + 1) * 64 + lane];
    const int l0 = labs[w * 64 + j + 0];
    const int l1 = labs[w * 64 + j + 1];
    float4* p0 = (float4*)&a[l0 * H + lane * 4];
    { float4 v = *p0; v.x += f0.x; v.y += f0.y; v.z += f0.z; v.w += f0.w; *p0 = v; }
    float4* p1 = (float4*)&a[l1 * H + lane * 4];
    { float4 v = *p1; v.x += f1.x; v.y += f1.y; v.z += f1.z; v.w += f1.w; *p1 = v; }
  }
  for (; j < nt; ++j) {
    float4 f = fbase[(size_t)j * 64 + lane];
    const int lab = labs[w * 64 + j];
    float4* p = (float4*)&a[lab * H + lane * 4];
    float4 v = *p; v.x += f.x; v.y += f.y; v.z += f.z; v.w += f.w; *p = v;
  }
  __syncthreads();

  // merge 4 wave slabs -> pp[b][seg][L][H], float4 granularity
  float4* op = (float4*)(ws_pp + (((size_t)b * 4 + seg) * L) * H);
  const float4* a0 = (const float4*)acc[0];
  const float4* a1 = (const float4*)acc[1];
  const float4* a2 = (const float4*)acc[2];
  const float4* a3 = (const float4*)acc[3];
  for (int e = tid; e < L * H / 4; e += 256) {
    float4 s0 = a0[e], s1 = a1[e], s2 = a2[e], s3 = a3[e];
    op[e] = make_float4(s0.x + s1.x + s2.x + s3.x,
                        s0.y + s1.y + s2.y + s3.y,
                        s0.z + s1.z + s2.z + s3.z,
                        s0.w + s1.w + s2.w + s3.w);
  }
  if (tid < L) ws_cntp[(b * 4 + seg) * L + tid] = cnt[tid];
}

// ---------------------------------------------------------------------------
// Kernel 2: partial dots. grid = B * 2 H-halves = 256 blocks, 256 thr,
// up to 4 tokens/thread; token-group k skipped by block-uniform k<nseg branch.
// 16 fma per uniform ds_read_b128. unroll-2 over cb bursts to overlap the
// next burst's feat loads (L3-latency) with the current fma batch.
__global__ __launch_bounds__(256) void dots_kernel(
    const float* __restrict__ feat, const int* __restrict__ dlen,
    const float* __restrict__ ws_pp, const int* __restrict__ ws_cntp,
    float* __restrict__ ws_dots) {
  __shared__ float pr[L * 128];
  __shared__ int cnts[L];

  const int bx = blockIdx.x;
  const int b = bx >> 1;
  const int half = bx & 1;
  const int tid = threadIdx.x;

  const int len = dlen[b];
  const int nseg = (len + 255) >> 8;   // 1..4 valid segments

  if (tid < L) {
    const int* cp = ws_cntp + b * 4 * L + tid;
    int c = 0;
    for (int s = 0; s < nseg; ++s) c += cp[s * L];
    cnts[tid] = c;
  }
  __syncthreads();

  const float* gp = ws_pp + ((size_t)b * 4 * L) * H + half * 128;
  for (int i = tid; i < L * 128; i += 256) {
    const int l = i >> 7, c = i & 127;
    float s = 0.f;
    for (int sg = 0; sg < nseg; ++sg) s += gp[(sg * L + l) * H + c];
    const int cn = cnts[l];
    pr[i] = s * (cn > 0 ? 1.f / (float)cn : 0.f);
  }
  __syncthreads();

  const float4* fv[4];
#pragma unroll
  for (int k = 0; k < 4; ++k) {
    const int t = k * 256 + tid;
    fv[k] = (const float4*)(feat + ((size_t)b * T + t) * H + half * 128);
  }

  float dot[4][L];
#pragma unroll
  for (int k = 0; k < 4; ++k)
#pragma unroll
    for (int l = 0; l < L; ++l) dot[k][l] = 0.f;

#pragma unroll 2
  for (int cb = 0; cb < 8; ++cb) {   // 4 quads (64B) per burst per token
    float4 f[4][4];
#pragma unroll
    for (int k = 0; k < 4; ++k) {
      if (k < nseg) {                // block-uniform: skip dead token groups
#pragma unroll
        for (int q = 0; q < 4; ++q) f[k][q] = fv[k][cb * 4 + q];
      }
    }
#pragma unroll
    for (int q = 0; q < 4; ++q) {
#pragma unroll
      for (int l = 0; l < L; ++l) {
        const float4 p = *(const float4*)&pr[l * 128 + cb * 16 + q * 4];
#pragma unroll
        for (int k = 0; k < 4; ++k) {
          if (k < nseg) {
            dot[k][l] += f[k][q].x * p.x + f[k][q].y * p.y +
                         f[k][q].z * p.z + f[k][q].w * p.w;
          }
        }
      }
    }
  }

#pragma unroll
  for (int k = 0; k < 4; ++k) {
    const int t = k * 256 + tid;
    if (k < nseg && t < len) {
      float4* d = (float4*)(ws_dots + (((size_t)half * B + b) * T + t) * L);
#pragma unroll
      for (int q = 0; q < 4; ++q)
        d[q] = make_float4(dot[k][q * 4], dot[k][q * 4 + 1],
                           dot[k][q * 4 + 2], dot[k][q * 4 + 3]);
    }
  }
}

// ---------------------------------------------------------------------------
// Kernel 3: combine halves, log-softmax, masked mean. grid = B*4 = 512 blocks.
__global__ __launch_bounds__(256) void loss_kernel(
    const int* __restrict__ dlen, const int* __restrict__ labels,
    const int* __restrict__ ws_cntp, const float* __restrict__ ws_dots,
    float* __restrict__ out) {
  __shared__ int cnts[L];
  __shared__ float red[256];

  const int b = blockIdx.x >> 2;
  const int seg = blockIdx.x & 3;
  const int tid = threadIdx.x;

  const int len = dlen[b];
  if (seg * 256 >= len) return;        // contributes exactly 0
  const int nseg = (len + 255) >> 8;

  if (tid < L) {
    const int* cp = ws_cntp + b * 4 * L + tid;
    int c = 0;
    for (int s = 0; s < nseg; ++s) c += cp[s * L];
    cnts[tid] = c;
  }
  __syncthreads();

  const int t = seg * 256 + tid;
  float tok = 0.f;

  if (t < len) {
    const float* d0 = ws_dots + ((size_t)b * T + t) * L;
    const float* d1 = d0 + (size_t)B * T * L;
    float lg[L];
#pragma unroll
    for (int l = 0; l < L; ++l) {
      const float d = d0[l] + d1[l];
      lg[l] = (cnts[l] > 0) ? d * INV_TEMP : NEG_INF;
    }
    float m = lg[0];
#pragma unroll
    for (int l = 1; l < L; ++l) m = fmaxf(m, lg[l]);
    float se = 0.f;
#pragma unroll
    for (int l = 0; l < L; ++l) se += expf(lg[l] - m);
    const float lsp = m + logf(se);

    const int lab = labels[(size_t)b * T + t];
    float pos = 0.f;
#pragma unroll
    for (int l = 0; l < L; ++l) pos += (l == lab) ? lg[l] : 0.f;

    tok = lsp - pos;
  }

  red[tid] = tok;
  __syncthreads();
#pragma unroll
  for (int s = 128; s > 0; s >>= 1) {
    if (tid < s) red[tid] += red[tid + s];
    __syncthreads();
  }
  if (tid == 0) atomicAdd(out, red[0] / ((float)len * (float)B));
}

extern "C" void kernel_launch(void* const* d_in, const int* in_sizes, int n_in,
                              void* d_out, int out_size, void* d_ws, size_t ws_size,
                              hipStream_t stream) {
  const float* feat = (const float*)d_in[0];
  const int* dlen = (const int*)d_in[1];
  const int* labels = (const int*)d_in[2];
  float* out = (float*)d_out;

  float* ws_pp = (float*)d_ws;                           // B*4*L*H floats
  int* ws_cntp = (int*)(ws_pp + (size_t)B * 4 * L * H);  // B*4*L ints
  float* ws_dots = (float*)(ws_cntp + (size_t)B * 4 * L);// 2*B*T*L floats

  hipMemsetAsync(out, 0, sizeof(float), stream);
  proto_kernel<<<B * 4, 256, 0, stream>>>(feat, dlen, labels, ws_pp, ws_cntp);
  dots_kernel<<<B * 2, 256, 0, stream>>>(feat, dlen, ws_pp, ws_cntp, ws_dots);
  loss_kernel<<<B * 4, 256, 0, stream>>>(dlen, labels, ws_cntp, ws_dots, out);
}

// Round 6
// 241.870 us; speedup vs baseline: 1.0030x; 1.0030x over previous
//
#include <hip/hip_runtime.h>
#include <math.h>

#define B 128
#define T 1024
#define H 256
#define L 16
#define INV_TEMP (1.0f/0.07f)
#define NEG_INF -1e30f

// ws layout (only seg<nseg regions are ever written/read -> no memset):
//   ws_pp   : float[B][4][L][H]   per-seg prototype partial sums   8 MB
//   ws_cntp : int[B][4][L]        per-seg label counts             32 KB

// ---------------------------------------------------------------------------
// Kernel 1 (R4-proven): prototype partial sums. grid = B*2 chunks*4 segs =
// 1024 blocks. Block owns a disjoint [b][seg][L][chunk*128..+128) slice ->
// plain stores, no atomics. Wave-private slabs, short (<=64 token) RMW chains.
__global__ __launch_bounds__(256) void proto_kernel(
    const float* __restrict__ feat, const int* __restrict__ dlen,
    const int* __restrict__ labels, float* __restrict__ ws_pp,
    int* __restrict__ ws_cntp) {
  __shared__ float acc[4][L * 128];   // 32 KB, wave-private slabs
  __shared__ int labs[256];
  __shared__ int cnt[L];

  const int bx = blockIdx.x;
  const int b = bx >> 3;
  const int chunk = (bx >> 2) & 1;
  const int seg = bx & 3;
  const int tid = threadIdx.x;
  const int w = tid >> 6;
  const int lane = tid & 63;

  const int len = dlen[b];
  if (seg * 256 >= len) return;   // invalid segment: consumers skip seg>=nseg

  for (int i = tid; i < 4 * L * 128; i += 256) ((float*)acc)[i] = 0.f;
  labs[tid] = labels[(size_t)b * T + seg * 256 + tid];
  if (tid < L) cnt[tid] = 0;
  __syncthreads();

  if (chunk == 0 && (seg * 256 + tid) < len) atomicAdd(&cnt[labs[tid]], 1);

  int nt = len - seg * 256 - w * 64;   // tokens this wave processes
  if (nt > 64) nt = 64;
  const float2* fbase = (const float2*)(feat +
      ((size_t)b * T + seg * 256 + w * 64) * H + chunk * 128);
  float* a = acc[w];

  int j = 0;
  for (; j + 4 <= nt; j += 4) {
    float2 f0 = fbase[(size_t)(j + 0) * (H / 2) + lane];
    float2 f1 = fbase[(size_t)(j + 1) * (H / 2) + lane];
    float2 f2 = fbase[(size_t)(j + 2) * (H / 2) + lane];
    float2 f3 = fbase[(size_t)(j + 3) * (H / 2) + lane];
    const int l0 = labs[w * 64 + j + 0];
    const int l1 = labs[w * 64 + j + 1];
    const int l2 = labs[w * 64 + j + 2];
    const int l3 = labs[w * 64 + j + 3];
    float2* p0 = (float2*)&a[l0 * 128 + lane * 2];
    { float2 v = *p0; v.x += f0.x; v.y += f0.y; *p0 = v; }
    float2* p1 = (float2*)&a[l1 * 128 + lane * 2];
    { float2 v = *p1; v.x += f1.x; v.y += f1.y; *p1 = v; }
    float2* p2 = (float2*)&a[l2 * 128 + lane * 2];
    { float2 v = *p2; v.x += f2.x; v.y += f2.y; *p2 = v; }
    float2* p3 = (float2*)&a[l3 * 128 + lane * 2];
    { float2 v = *p3; v.x += f3.x; v.y += f3.y; *p3 = v; }
  }
  for (; j < nt; ++j) {
    float2 f = fbase[(size_t)j * (H / 2) + lane];
    const int lab = labs[w * 64 + j];
    float2* p = (float2*)&a[lab * 128 + lane * 2];
    float2 v = *p; v.x += f.x; v.y += f.y; *p = v;
  }
  __syncthreads();

  float* op = ws_pp + (((size_t)b * 4 + seg) * L) * H + chunk * 128;
  for (int e = tid; e < L * 128; e += 256) {
    const float s = acc[0][e] + acc[1][e] + acc[2][e] + acc[3][e];
    op[(e >> 7) * H + (e & 127)] = s;
  }
  if (chunk == 0 && tid < L) ws_cntp[(b * 4 + seg) * L + tid] = cnt[tid];
}

// ---------------------------------------------------------------------------
// Kernel 2 (fused dots + softmax + loss). grid = B * 2 token-groups of 512.
// Block stages the MERGED, DIVIDED prototype [L][256] (16 KB) in LDS, each
// thread owns 2 tokens (t, t+256), full-H dot -> 8 fma per uniform
// ds_read_b128. Softmax + own-label pick + block reduce + one atomic.
// No ws_dots round-trip, no third kernel.
__global__ __launch_bounds__(256) void dots_loss_kernel(
    const float* __restrict__ feat, const int* __restrict__ dlen,
    const int* __restrict__ labels, const float* __restrict__ ws_pp,
    const int* __restrict__ ws_cntp, float* __restrict__ out) {
  __shared__ float pr[L * H];   // 16 KB merged prototypes
  __shared__ int cnts[L];
  __shared__ float red[256];

  const int bx = blockIdx.x;
  const int b = bx >> 1;
  const int g = bx & 1;          // 512-token group
  const int tid = threadIdx.x;

  const int len = dlen[b];
  if (g * 512 >= len) return;          // whole group invalid: contributes 0
  const int nseg = (len + 255) >> 8;

  if (tid < L) {
    const int* cp = ws_cntp + b * 4 * L + tid;
    int c = 0;
    for (int s = 0; s < nseg; ++s) c += cp[s * L];
    cnts[tid] = c;
  }
  __syncthreads();

  const float* gp = ws_pp + ((size_t)b * 4 * L) * H;
  for (int i = tid; i < L * H; i += 256) {
    const int l = i >> 8, c = i & 255;
    float s = 0.f;
    for (int sg = 0; sg < nseg; ++sg) s += gp[(sg * L + l) * H + c];
    const int cn = cnts[l];
    pr[i] = s * (cn > 0 ? 1.f / (float)cn : 0.f);
  }
  __syncthreads();

  const int t0 = g * 512 + tid;        // always < T
  const int t1 = t0 + 256;
  const bool v1 = (g * 512 + 256) < len;   // block-uniform group validity
  const float4* fv0 = (const float4*)(feat + ((size_t)b * T + t0) * H);
  const float4* fv1 = (const float4*)(feat + ((size_t)b * T + t1) * H);

  float dot0[L], dot1[L];
#pragma unroll
  for (int l = 0; l < L; ++l) { dot0[l] = 0.f; dot1[l] = 0.f; }

#pragma unroll 2
  for (int cb = 0; cb < 16; ++cb) {    // 4 quads (64B) per burst per token
    float4 f0[4], f1[4];
#pragma unroll
    for (int q = 0; q < 4; ++q) f0[q] = fv0[cb * 4 + q];
    if (v1) {
#pragma unroll
      for (int q = 0; q < 4; ++q) f1[q] = fv1[cb * 4 + q];
    }
#pragma unroll
    for (int q = 0; q < 4; ++q) {
#pragma unroll
      for (int l = 0; l < L; ++l) {
        const float4 p = *(const float4*)&pr[l * H + cb * 16 + q * 4];
        dot0[l] += f0[q].x * p.x + f0[q].y * p.y + f0[q].z * p.z + f0[q].w * p.w;
        if (v1)
          dot1[l] += f1[q].x * p.x + f1[q].y * p.y + f1[q].z * p.z + f1[q].w * p.w;
      }
    }
  }

  float tok = 0.f;
  // token t0
  if (t0 < len) {
    float lg[L];
#pragma unroll
    for (int l = 0; l < L; ++l)
      lg[l] = (cnts[l] > 0) ? dot0[l] * INV_TEMP : NEG_INF;
    float m = lg[0];
#pragma unroll
    for (int l = 1; l < L; ++l) m = fmaxf(m, lg[l]);
    float se = 0.f;
#pragma unroll
    for (int l = 0; l < L; ++l) se += expf(lg[l] - m);
    const float lsp = m + logf(se);
    const int lab = labels[(size_t)b * T + t0];
    float pos = 0.f;
#pragma unroll
    for (int l = 0; l < L; ++l) pos += (l == lab) ? lg[l] : 0.f;
    tok += lsp - pos;
  }
  // token t1
  if (v1 && t1 < len) {
    float lg[L];
#pragma unroll
    for (int l = 0; l < L; ++l)
      lg[l] = (cnts[l] > 0) ? dot1[l] * INV_TEMP : NEG_INF;
    float m = lg[0];
#pragma unroll
    for (int l = 1; l < L; ++l) m = fmaxf(m, lg[l]);
    float se = 0.f;
#pragma unroll
    for (int l = 0; l < L; ++l) se += expf(lg[l] - m);
    const float lsp = m + logf(se);
    const int lab = labels[(size_t)b * T + t1];
    float pos = 0.f;
#pragma unroll
    for (int l = 0; l < L; ++l) pos += (l == lab) ? lg[l] : 0.f;
    tok += lsp - pos;
  }

  red[tid] = tok;
  __syncthreads();
#pragma unroll
  for (int s = 128; s > 0; s >>= 1) {
    if (tid < s) red[tid] += red[tid + s];
    __syncthreads();
  }
  if (tid == 0) atomicAdd(out, red[0] / ((float)len * (float)B));
}

extern "C" void kernel_launch(void* const* d_in, const int* in_sizes, int n_in,
                              void* d_out, int out_size, void* d_ws, size_t ws_size,
                              hipStream_t stream) {
  const float* feat = (const float*)d_in[0];
  const int* dlen = (const int*)d_in[1];
  const int* labels = (const int*)d_in[2];
  float* out = (float*)d_out;

  float* ws_pp = (float*)d_ws;                           // B*4*L*H floats
  int* ws_cntp = (int*)(ws_pp + (size_t)B * 4 * L * H);  // B*4*L ints

  hipMemsetAsync(out, 0, sizeof(float), stream);
  proto_kernel<<<B * 8, 256, 0, stream>>>(feat, dlen, labels, ws_pp, ws_cntp);
  dots_loss_kernel<<<B * 2, 256, 0, stream>>>(feat, dlen, labels, ws_pp,
                                              ws_cntp, out);
}

// Round 7
// 237.614 us; speedup vs baseline: 1.0210x; 1.0179x over previous
//
#include <hip/hip_runtime.h>
#include <math.h>

#define B 128
#define T 1024
#define H 256
#define L 16
#define INV_TEMP (1.0f/0.07f)
#define NEG_INF -1e30f

// ws layout (only seg<nseg regions are ever written/read -> no memset):
//   ws_pp   : float[B][4][L][H]   per-seg prototype partial sums   8 MB
//   ws_cntp : int[B][4][L]        per-seg label counts             32 KB
//   ws_dots : float[2][B][T][L]   partial dots per H-half          16 MB

// ---------------------------------------------------------------------------
// Kernel 1 (R4-proven): prototype partial sums. grid = B*2 chunks*4 segs =
// 1024 blocks. Block owns a disjoint [b][seg][L][chunk*128..+128) slice ->
// plain stores, no atomics. Wave-private slabs, short (<=64 token) RMW chains.
// Block 0 also zeroes out[0] (stream-ordered before loss_kernel's atomics).
__global__ __launch_bounds__(256) void proto_kernel(
    const float* __restrict__ feat, const int* __restrict__ dlen,
    const int* __restrict__ labels, float* __restrict__ ws_pp,
    int* __restrict__ ws_cntp, float* __restrict__ out) {
  __shared__ float acc[4][L * 128];   // 32 KB, wave-private slabs
  __shared__ int labs[256];
  __shared__ int cnt[L];

  const int bx = blockIdx.x;
  const int b = bx >> 3;
  const int chunk = (bx >> 2) & 1;
  const int seg = bx & 3;
  const int tid = threadIdx.x;
  const int w = tid >> 6;
  const int lane = tid & 63;

  if (bx == 0 && tid == 0) out[0] = 0.f;   // replaces the memset dispatch

  const int len = dlen[b];
  if (seg * 256 >= len) return;   // invalid segment: consumers skip seg>=nseg

  for (int i = tid; i < 4 * L * 128; i += 256) ((float*)acc)[i] = 0.f;
  labs[tid] = labels[(size_t)b * T + seg * 256 + tid];
  if (tid < L) cnt[tid] = 0;
  __syncthreads();

  if (chunk == 0 && (seg * 256 + tid) < len) atomicAdd(&cnt[labs[tid]], 1);

  int nt = len - seg * 256 - w * 64;   // tokens this wave processes
  if (nt > 64) nt = 64;
  const float2* fbase = (const float2*)(feat +
      ((size_t)b * T + seg * 256 + w * 64) * H + chunk * 128);
  float* a = acc[w];

  int j = 0;
  for (; j + 4 <= nt; j += 4) {
    float2 f0 = fbase[(size_t)(j + 0) * (H / 2) + lane];
    float2 f1 = fbase[(size_t)(j + 1) * (H / 2) + lane];
    float2 f2 = fbase[(size_t)(j + 2) * (H / 2) + lane];
    float2 f3 = fbase[(size_t)(j + 3) * (H / 2) + lane];
    const int l0 = labs[w * 64 + j + 0];
    const int l1 = labs[w * 64 + j + 1];
    const int l2 = labs[w * 64 + j + 2];
    const int l3 = labs[w * 64 + j + 3];
    float2* p0 = (float2*)&a[l0 * 128 + lane * 2];
    { float2 v = *p0; v.x += f0.x; v.y += f0.y; *p0 = v; }
    float2* p1 = (float2*)&a[l1 * 128 + lane * 2];
    { float2 v = *p1; v.x += f1.x; v.y += f1.y; *p1 = v; }
    float2* p2 = (float2*)&a[l2 * 128 + lane * 2];
    { float2 v = *p2; v.x += f2.x; v.y += f2.y; *p2 = v; }
    float2* p3 = (float2*)&a[l3 * 128 + lane * 2];
    { float2 v = *p3; v.x += f3.x; v.y += f3.y; *p3 = v; }
  }
  for (; j < nt; ++j) {
    float2 f = fbase[(size_t)j * (H / 2) + lane];
    const int lab = labs[w * 64 + j];
    float2* p = (float2*)&a[lab * 128 + lane * 2];
    float2 v = *p; v.x += f.x; v.y += f.y; *p = v;
  }
  __syncthreads();

  float* op = ws_pp + (((size_t)b * 4 + seg) * L) * H + chunk * 128;
  for (int e = tid; e < L * 128; e += 256) {
    const float s = acc[0][e] + acc[1][e] + acc[2][e] + acc[3][e];
    op[(e >> 7) * H + (e & 127)] = s;
  }
  if (chunk == 0 && tid < L) ws_cntp[(b * 4 + seg) * L + tid] = cnt[tid];
}

// ---------------------------------------------------------------------------
// Kernel 2 (R4-proven shape): partial dots. grid = B * 2 H-halves = 256
// blocks, 4 tokens/thread -> 16 fma per uniform ds_read_b128 (the measured
// sweet spot; 2 tok/thread full-H regressed +16us in R6). unroll-2 on cb to
// overlap the next 64B/lane line fetch with the current fma batch.
__global__ __launch_bounds__(256) void dots_kernel(
    const float* __restrict__ feat, const int* __restrict__ dlen,
    const float* __restrict__ ws_pp, const int* __restrict__ ws_cntp,
    float* __restrict__ ws_dots) {
  __shared__ float pr[L * 128];
  __shared__ int cnts[L];

  const int bx = blockIdx.x;
  const int b = bx >> 1;
  const int half = bx & 1;
  const int tid = threadIdx.x;

  const int len = dlen[b];
  const int nseg = (len + 255) >> 8;   // 1..4 valid segments

  if (tid < L) {
    const int* cp = ws_cntp + b * 4 * L + tid;
    int c = 0;
    for (int s = 0; s < nseg; ++s) c += cp[s * L];
    cnts[tid] = c;
  }
  __syncthreads();

  const float* gp = ws_pp + ((size_t)b * 4 * L) * H + half * 128;
  for (int i = tid; i < L * 128; i += 256) {
    const int l = i >> 7, c = i & 127;
    float s = 0.f;
    for (int sg = 0; sg < nseg; ++sg) s += gp[(sg * L + l) * H + c];
    const int cn = cnts[l];
    pr[i] = s * (cn > 0 ? 1.f / (float)cn : 0.f);
  }
  __syncthreads();

  const float4* fv[4];
#pragma unroll
  for (int k = 0; k < 4; ++k) {
    const int t = k * 256 + tid;
    fv[k] = (const float4*)(feat + ((size_t)b * T + t) * H + half * 128);
  }

  float dot[4][L];
#pragma unroll
  for (int k = 0; k < 4; ++k)
#pragma unroll
    for (int l = 0; l < L; ++l) dot[k][l] = 0.f;

#pragma unroll 2
  for (int cb = 0; cb < 8; ++cb) {   // 4 quads (64B line) per burst per token
    float4 f[4][4];
#pragma unroll
    for (int k = 0; k < 4; ++k) {
      if (k < nseg) {                // block-uniform: skip dead token groups
#pragma unroll
        for (int q = 0; q < 4; ++q) f[k][q] = fv[k][cb * 4 + q];
      }
    }
#pragma unroll
    for (int q = 0; q < 4; ++q) {
#pragma unroll
      for (int l = 0; l < L; ++l) {
        const float4 p = *(const float4*)&pr[l * 128 + cb * 16 + q * 4];
#pragma unroll
        for (int k = 0; k < 4; ++k) {
          if (k < nseg) {
            dot[k][l] += f[k][q].x * p.x + f[k][q].y * p.y +
                         f[k][q].z * p.z + f[k][q].w * p.w;
          }
        }
      }
    }
  }

#pragma unroll
  for (int k = 0; k < 4; ++k) {
    const int t = k * 256 + tid;
    if (k < nseg && t < len) {
      float4* d = (float4*)(ws_dots + (((size_t)half * B + b) * T + t) * L);
#pragma unroll
      for (int q = 0; q < 4; ++q)
        d[q] = make_float4(dot[k][q * 4], dot[k][q * 4 + 1],
                           dot[k][q * 4 + 2], dot[k][q * 4 + 3]);
    }
  }
}

// ---------------------------------------------------------------------------
// Kernel 3: combine halves, log-softmax, masked mean. grid = B*4 = 512 blocks.
__global__ __launch_bounds__(256) void loss_kernel(
    const int* __restrict__ dlen, const int* __restrict__ labels,
    const int* __restrict__ ws_cntp, const float* __restrict__ ws_dots,
    float* __restrict__ out) {
  __shared__ int cnts[L];
  __shared__ float red[256];

  const int b = blockIdx.x >> 2;
  const int seg = blockIdx.x & 3;
  const int tid = threadIdx.x;

  const int len = dlen[b];
  if (seg * 256 >= len) return;        // contributes exactly 0
  const int nseg = (len + 255) >> 8;

  if (tid < L) {
    const int* cp = ws_cntp + b * 4 * L + tid;
    int c = 0;
    for (int s = 0; s < nseg; ++s) c += cp[s * L];
    cnts[tid] = c;
  }
  __syncthreads();

  const int t = seg * 256 + tid;
  float tok = 0.f;

  if (t < len) {
    const float4* d0 = (const float4*)(ws_dots + ((size_t)b * T + t) * L);
    const float4* d1 = (const float4*)((const float*)d0 + (size_t)B * T * L);
    float4 a0 = d0[0], a1 = d0[1], a2 = d0[2], a3 = d0[3];
    float4 b0 = d1[0], b1 = d1[1], b2 = d1[2], b3 = d1[3];
    float dsum[L] = {
      a0.x + b0.x, a0.y + b0.y, a0.z + b0.z, a0.w + b0.w,
      a1.x + b1.x, a1.y + b1.y, a1.z + b1.z, a1.w + b1.w,
      a2.x + b2.x, a2.y + b2.y, a2.z + b2.z, a2.w + b2.w,
      a3.x + b3.x, a3.y + b3.y, a3.z + b3.z, a3.w + b3.w };
    float lg[L];
#pragma unroll
    for (int l = 0; l < L; ++l)
      lg[l] = (cnts[l] > 0) ? dsum[l] * INV_TEMP : NEG_INF;
    float m = lg[0];
#pragma unroll
    for (int l = 1; l < L; ++l) m = fmaxf(m, lg[l]);
    float se = 0.f;
#pragma unroll
    for (int l = 0; l < L; ++l) se += expf(lg[l] - m);
    const float lsp = m + logf(se);

    const int lab = labels[(size_t)b * T + t];
    float pos = 0.f;
#pragma unroll
    for (int l = 0; l < L; ++l) pos += (l == lab) ? lg[l] : 0.f;

    tok = lsp - pos;
  }

  red[tid] = tok;
  __syncthreads();
#pragma unroll
  for (int s = 128; s > 0; s >>= 1) {
    if (tid < s) red[tid] += red[tid + s];
    __syncthreads();
  }
  if (tid == 0) atomicAdd(out, red[0] / ((float)len * (float)B));
}

extern "C" void kernel_launch(void* const* d_in, const int* in_sizes, int n_in,
                              void* d_out, int out_size, void* d_ws, size_t ws_size,
                              hipStream_t stream) {
  const float* feat = (const float*)d_in[0];
  const int* dlen = (const int*)d_in[1];
  const int* labels = (const int*)d_in[2];
  float* out = (float*)d_out;

  float* ws_pp = (float*)d_ws;                           // B*4*L*H floats
  int* ws_cntp = (int*)(ws_pp + (size_t)B * 4 * L * H);  // B*4*L ints
  float* ws_dots = (float*)(ws_cntp + (size_t)B * 4 * L);// 2*B*T*L floats

  proto_kernel<<<B * 8, 256, 0, stream>>>(feat, dlen, labels, ws_pp, ws_cntp, out);
  dots_kernel<<<B * 2, 256, 0, stream>>>(feat, dlen, ws_pp, ws_cntp, ws_dots);
  loss_kernel<<<B * 4, 256, 0, stream>>>(dlen, labels, ws_cntp, ws_dots, out);
}

// Round 8
// 228.211 us; speedup vs baseline: 1.0631x; 1.0412x over previous
//
#include <hip/hip_runtime.h>
#include <math.h>

#define B 128
#define T 1024
#define H 256
#define L 16
#define INV_TEMP (1.0f/0.07f)
#define NEG_INF -1e30f

// ws layout (only seg<nseg regions are ever written/read -> no memset):
//   ws_pp   : float[B][4][L][H]   per-seg prototype partial sums   8 MB
//   ws_cntp : int[B][4][L]        per-seg label counts             32 KB
//   ws_dots : float[2][B][T][L]   partial dots per H-half          16 MB

// ---------------------------------------------------------------------------
// Kernel 1: prototype partial sums. grid = B * 2 chunks * 4 segs = 1024
// blocks. Block owns a disjoint [b][seg][L][chunk*128..+128) slice -> plain
// stores, no atomics. Wave-private slabs, short (<=64 token) RMW chains
// (R5 showed long 256-token chains regress). Block 0 zeroes out[0]
// (stream-ordered before loss_kernel's atomics; replaces memset dispatch).
__global__ __launch_bounds__(256) void proto_kernel(
    const float* __restrict__ feat, const int* __restrict__ dlen,
    const int* __restrict__ labels, float* __restrict__ ws_pp,
    int* __restrict__ ws_cntp, float* __restrict__ out) {
  __shared__ float acc[4][L * 128];   // 32 KB, wave-private slabs
  __shared__ int labs[256];
  __shared__ int cnt[L];

  const int bx = blockIdx.x;
  const int b = bx >> 3;
  const int chunk = (bx >> 2) & 1;
  const int seg = bx & 3;
  const int tid = threadIdx.x;
  const int w = tid >> 6;
  const int lane = tid & 63;

  if (bx == 0 && tid == 0) out[0] = 0.f;

  const int len = dlen[b];
  if (seg * 256 >= len) return;   // invalid segment: consumers skip seg>=nseg

  for (int i = tid; i < 4 * L * 128; i += 256) ((float*)acc)[i] = 0.f;
  labs[tid] = labels[(size_t)b * T + seg * 256 + tid];
  if (tid < L) cnt[tid] = 0;
  __syncthreads();

  if (chunk == 0 && (seg * 256 + tid) < len) atomicAdd(&cnt[labs[tid]], 1);

  int nt = len - seg * 256 - w * 64;   // tokens this wave processes
  if (nt > 64) nt = 64;
  const float2* fbase = (const float2*)(feat +
      ((size_t)b * T + seg * 256 + w * 64) * H + chunk * 128);
  float* a = acc[w];

  int j = 0;
  for (; j + 4 <= nt; j += 4) {
    float2 f0 = fbase[(size_t)(j + 0) * (H / 2) + lane];
    float2 f1 = fbase[(size_t)(j + 1) * (H / 2) + lane];
    float2 f2 = fbase[(size_t)(j + 2) * (H / 2) + lane];
    float2 f3 = fbase[(size_t)(j + 3) * (H / 2) + lane];
    const int l0 = labs[w * 64 + j + 0];
    const int l1 = labs[w * 64 + j + 1];
    const int l2 = labs[w * 64 + j + 2];
    const int l3 = labs[w * 64 + j + 3];
    float2* p0 = (float2*)&a[l0 * 128 + lane * 2];
    { float2 v = *p0; v.x += f0.x; v.y += f0.y; *p0 = v; }
    float2* p1 = (float2*)&a[l1 * 128 + lane * 2];
    { float2 v = *p1; v.x += f1.x; v.y += f1.y; *p1 = v; }
    float2* p2 = (float2*)&a[l2 * 128 + lane * 2];
    { float2 v = *p2; v.x += f2.x; v.y += f2.y; *p2 = v; }
    float2* p3 = (float2*)&a[l3 * 128 + lane * 2];
    { float2 v = *p3; v.x += f3.x; v.y += f3.y; *p3 = v; }
  }
  for (; j < nt; ++j) {
    float2 f = fbase[(size_t)j * (H / 2) + lane];
    const int lab = labs[w * 64 + j];
    float2* p = (float2*)&a[lab * 128 + lane * 2];
    float2 v = *p; v.x += f.x; v.y += f.y; *p = v;
  }
  __syncthreads();

  float* op = ws_pp + (((size_t)b * 4 + seg) * L) * H + chunk * 128;
  for (int e = tid; e < L * 128; e += 256) {
    const float s = acc[0][e] + acc[1][e] + acc[2][e] + acc[3][e];
    op[(e >> 7) * H + (e & 127)] = s;
  }
  if (chunk == 0 && tid < L) ws_cntp[(b * 4 + seg) * L + tid] = cnt[tid];
}

// ---------------------------------------------------------------------------
// Kernel 2: partial dots. grid = B * 2 H-halves = 256 blocks, 256 thr,
// up to 4 tokens/thread; token-group k skipped by block-uniform k<nseg branch.
// 16 fma per uniform ds_read_b128. NO forced unroll on cb: unroll-2 doubled
// staging registers and regressed +11..16us in R5/R7.
__global__ __launch_bounds__(256) void dots_kernel(
    const float* __restrict__ feat, const int* __restrict__ dlen,
    const float* __restrict__ ws_pp, const int* __restrict__ ws_cntp,
    float* __restrict__ ws_dots) {
  __shared__ float pr[L * 128];
  __shared__ int cnts[L];

  const int bx = blockIdx.x;
  const int b = bx >> 1;
  const int half = bx & 1;
  const int tid = threadIdx.x;

  const int len = dlen[b];
  const int nseg = (len + 255) >> 8;   // 1..4 valid segments

  if (tid < L) {
    const int* cp = ws_cntp + b * 4 * L + tid;
    int c = 0;
    for (int s = 0; s < nseg; ++s) c += cp[s * L];
    cnts[tid] = c;
  }
  __syncthreads();

  const float* gp = ws_pp + ((size_t)b * 4 * L) * H + half * 128;
  for (int i = tid; i < L * 128; i += 256) {
    const int l = i >> 7, c = i & 127;
    float s = 0.f;
    for (int sg = 0; sg < nseg; ++sg) s += gp[(sg * L + l) * H + c];
    const int cn = cnts[l];
    pr[i] = s * (cn > 0 ? 1.f / (float)cn : 0.f);
  }
  __syncthreads();

  const float4* fv[4];
#pragma unroll
  for (int k = 0; k < 4; ++k) {
    const int t = k * 256 + tid;
    fv[k] = (const float4*)(feat + ((size_t)b * T + t) * H + half * 128);
  }

  float dot[4][L];
#pragma unroll
  for (int k = 0; k < 4; ++k)
#pragma unroll
    for (int l = 0; l < L; ++l) dot[k][l] = 0.f;

  for (int cb = 0; cb < 8; ++cb) {   // 4 quads (64B) per burst per token
    float4 f[4][4];
#pragma unroll
    for (int k = 0; k < 4; ++k) {
      if (k < nseg) {                // block-uniform: skip dead token groups
#pragma unroll
        for (int q = 0; q < 4; ++q) f[k][q] = fv[k][cb * 4 + q];
      }
    }
#pragma unroll
    for (int q = 0; q < 4; ++q) {
#pragma unroll
      for (int l = 0; l < L; ++l) {
        const float4 p = *(const float4*)&pr[l * 128 + cb * 16 + q * 4];
#pragma unroll
        for (int k = 0; k < 4; ++k) {
          if (k < nseg) {
            dot[k][l] += f[k][q].x * p.x + f[k][q].y * p.y +
                         f[k][q].z * p.z + f[k][q].w * p.w;
          }
        }
      }
    }
  }

#pragma unroll
  for (int k = 0; k < 4; ++k) {
    const int t = k * 256 + tid;
    if (k < nseg && t < len) {
      float4* d = (float4*)(ws_dots + (((size_t)half * B + b) * T + t) * L);
#pragma unroll
      for (int q = 0; q < 4; ++q)
        d[q] = make_float4(dot[k][q * 4], dot[k][q * 4 + 1],
                           dot[k][q * 4 + 2], dot[k][q * 4 + 3]);
    }
  }
}

// ---------------------------------------------------------------------------
// Kernel 3: combine halves, log-softmax, masked mean. grid = B*4 = 512 blocks.
__global__ __launch_bounds__(256) void loss_kernel(
    const int* __restrict__ dlen, const int* __restrict__ labels,
    const int* __restrict__ ws_cntp, const float* __restrict__ ws_dots,
    float* __restrict__ out) {
  __shared__ int cnts[L];
  __shared__ float red[256];

  const int b = blockIdx.x >> 2;
  const int seg = blockIdx.x & 3;
  const int tid = threadIdx.x;

  const int len = dlen[b];
  if (seg * 256 >= len) return;        // contributes exactly 0
  const int nseg = (len + 255) >> 8;

  if (tid < L) {
    const int* cp = ws_cntp + b * 4 * L + tid;
    int c = 0;
    for (int s = 0; s < nseg; ++s) c += cp[s * L];
    cnts[tid] = c;
  }
  __syncthreads();

  const int t = seg * 256 + tid;
  float tok = 0.f;

  if (t < len) {
    const float* d0 = ws_dots + ((size_t)b * T + t) * L;
    const float* d1 = d0 + (size_t)B * T * L;
    float lg[L];
#pragma unroll
    for (int l = 0; l < L; ++l) {
      const float d = d0[l] + d1[l];
      lg[l] = (cnts[l] > 0) ? d * INV_TEMP : NEG_INF;
    }
    float m = lg[0];
#pragma unroll
    for (int l = 1; l < L; ++l) m = fmaxf(m, lg[l]);
    float se = 0.f;
#pragma unroll
    for (int l = 0; l < L; ++l) se += expf(lg[l] - m);
    const float lsp = m + logf(se);

    const int lab = labels[(size_t)b * T + t];
    float pos = 0.f;
#pragma unroll
    for (int l = 0; l < L; ++l) pos += (l == lab) ? lg[l] : 0.f;

    tok = lsp - pos;
  }

  red[tid] = tok;
  __syncthreads();
#pragma unroll
  for (int s = 128; s > 0; s >>= 1) {
    if (tid < s) red[tid] += red[tid + s];
    __syncthreads();
  }
  if (tid == 0) atomicAdd(out, red[0] / ((float)len * (float)B));
}

extern "C" void kernel_launch(void* const* d_in, const int* in_sizes, int n_in,
                              void* d_out, int out_size, void* d_ws, size_t ws_size,
                              hipStream_t stream) {
  const float* feat = (const float*)d_in[0];
  const int* dlen = (const int*)d_in[1];
  const int* labels = (const int*)d_in[2];
  float* out = (float*)d_out;

  float* ws_pp = (float*)d_ws;                           // B*4*L*H floats
  int* ws_cntp = (int*)(ws_pp + (size_t)B * 4 * L * H);  // B*4*L ints
  float* ws_dots = (float*)(ws_cntp + (size_t)B * 4 * L);// 2*B*T*L floats

  proto_kernel<<<B * 8, 256, 0, stream>>>(feat, dlen, labels, ws_pp, ws_cntp, out);
  dots_kernel<<<B * 2, 256, 0, stream>>>(feat, dlen, ws_pp, ws_cntp, ws_dots);
  loss_kernel<<<B * 4, 256, 0, stream>>>(dlen, labels, ws_cntp, ws_dots, out);
}